// Round 1
// baseline (851.221 us; speedup 1.0000x reference)
//
#include <hip/hip_runtime.h>

// ---------------------------------------------------------------------------
// Fused attention block: qkv GEMM -> RoPE -> causal SDPA -> out GEMM
// B=2 S=2048 D=1024 H=16 DH=64. bf16 MFMA for GEMMs, fp32 flash attention.
// ---------------------------------------------------------------------------

typedef __bf16 bf16x8 __attribute__((ext_vector_type(8)));
typedef float f32x4 __attribute__((ext_vector_type(4)));

__device__ __forceinline__ unsigned short f2b(float f) {
  unsigned int u = __builtin_bit_cast(unsigned int, f);
  unsigned int lsb = (u >> 16) & 1u;
  u += 0x7fffu + lsb;                 // round-to-nearest-even
  return (unsigned short)(u >> 16);
}
__device__ __forceinline__ float b2f(unsigned short h) {
  unsigned int u = ((unsigned int)h) << 16;
  return __builtin_bit_cast(float, u);
}

// --------------------------- fp32 -> bf16 convert ---------------------------
__global__ __launch_bounds__(256) void convert_bf16(const float* __restrict__ src,
                                                    unsigned short* __restrict__ dst,
                                                    int n) {
  int i = (blockIdx.x * 256 + threadIdx.x) * 4;
  if (i + 3 < n) {
    float4 v = *(const float4*)&src[i];
    ushort4 o;
    o.x = f2b(v.x); o.y = f2b(v.y); o.z = f2b(v.z); o.w = f2b(v.w);
    *(ushort4*)&dst[i] = o;
  }
}

// -------------------- transpose [K][N] f32 -> [N][K] bf16 -------------------
__global__ __launch_bounds__(256) void transpose_f32_bf16(const float* __restrict__ src,
                                                          unsigned short* __restrict__ dst,
                                                          int K, int N) {
  __shared__ float tile[32][33];
  int n0 = blockIdx.x * 32, k0 = blockIdx.y * 32;
  int c = threadIdx.x & 31, r4 = threadIdx.x >> 5;
#pragma unroll
  for (int p = 0; p < 4; ++p) {
    int r = r4 + p * 8;
    tile[r][c] = src[(size_t)(k0 + r) * N + n0 + c];
  }
  __syncthreads();
#pragma unroll
  for (int p = 0; p < 4; ++p) {
    int r = r4 + p * 8;
    dst[(size_t)(n0 + r) * K + k0 + c] = f2b(tile[c][r]);
  }
}

// --------------------------- bf16 MFMA GEMM --------------------------------
// C[M][N] (f32) = A[M][K] (bf16, row-major) * B, with B given as BT[N][K] bf16.
// 128x128 tile, BK=32, 256 threads = 4 waves (2x2), each wave 64x64 = 4x4
// fragments of 16x16x32 MFMA.
__global__ __launch_bounds__(256) void gemm_bf16_bt(const unsigned short* __restrict__ A,
                                                    const unsigned short* __restrict__ BT,
                                                    float* __restrict__ C,
                                                    int M, int N, int K) {
  __shared__ unsigned short As[128][40];  // +8 pad: conflict-free ds_read_b128
  __shared__ unsigned short Bs[128][40];
  const int tid = threadIdx.x;
  const int m0 = blockIdx.y * 128, n0 = blockIdx.x * 128;
  const int lane = tid & 63, wid = tid >> 6;
  const int wm = (wid >> 1) * 64, wn = (wid & 1) * 64;
  const int fr = lane & 15, oct = lane >> 4;

  f32x4 acc[4][4] = {};

  for (int k0 = 0; k0 < K; k0 += 32) {
    __syncthreads();
#pragma unroll
    for (int p = 0; p < 2; ++p) {
      int i = p * 256 + tid;
      int row = i >> 2, kc = (i & 3) * 8;
      *(uint4*)&As[row][kc] = *(const uint4*)&A[(size_t)(m0 + row) * K + k0 + kc];
      *(uint4*)&Bs[row][kc] = *(const uint4*)&BT[(size_t)(n0 + row) * K + k0 + kc];
    }
    __syncthreads();
    bf16x8 af[4], bq[4];
#pragma unroll
    for (int i = 0; i < 4; ++i)
      af[i] = __builtin_bit_cast(bf16x8, *(const uint4*)&As[wm + i * 16 + fr][oct * 8]);
#pragma unroll
    for (int j = 0; j < 4; ++j)
      bq[j] = __builtin_bit_cast(bf16x8, *(const uint4*)&Bs[wn + j * 16 + fr][oct * 8]);
#pragma unroll
    for (int i = 0; i < 4; ++i)
#pragma unroll
      for (int j = 0; j < 4; ++j)
        acc[i][j] = __builtin_amdgcn_mfma_f32_16x16x32_bf16(af[i], bq[j], acc[i][j], 0, 0, 0);
  }

#pragma unroll
  for (int i = 0; i < 4; ++i)
#pragma unroll
    for (int j = 0; j < 4; ++j)
#pragma unroll
      for (int r = 0; r < 4; ++r)
        C[(size_t)(m0 + wm + i * 16 + oct * 4 + r) * N + n0 + wn + j * 16 + fr] =
            acc[i][j][r];
}

// ------------------------------- RoPE (in place) ----------------------------
// qkv [4096][3072] f32; q at col 0, k at col 1024. freqs [2048][64].
// d<32: x' = x*cos(f_d) - y*sin(f_d); d>=32: y' = y*cos(f_d32) + x*sin(f_d32)
__global__ __launch_bounds__(256) void rope_kernel(float* __restrict__ qkv,
                                                   const float* __restrict__ freqs) {
  int i = blockIdx.x * 256 + threadIdx.x;   // [0, 4096*16*32)
  int t = i >> 9;
  int rem = i & 511;
  int h = rem >> 5, d = rem & 31;
  int s = t & 2047;
  float f_lo = freqs[s * 64 + d], f_hi = freqs[s * 64 + d + 32];
  float cl = cosf(f_lo), sl = sinf(f_lo);
  float ch = cosf(f_hi), sh = sinf(f_hi);
  float* row = qkv + (size_t)t * 3072;
  int qo = h * 64 + d;
  float qlo = row[qo], qhi = row[qo + 32];
  row[qo]      = qlo * cl - qhi * sl;
  row[qo + 32] = qhi * ch + qlo * sh;
  int ko = 1024 + h * 64 + d;
  float klo = row[ko], khi = row[ko + 32];
  row[ko]      = klo * cl - khi * sl;
  row[ko + 32] = khi * ch + klo * sh;
}

// --------------------------- causal flash attention -------------------------
// One workgroup: (b, h, 64-row q-block). fp32 scores/PV, online softmax.
// Reads post-RoPE qkv f32; writes attention output as bf16 [4096][1024].
__global__ __launch_bounds__(256) void attn_kernel(const float* __restrict__ qkv,
                                                   unsigned short* __restrict__ attnb) {
  const int qb = 31 - blockIdx.x;   // heavy (large qb) blocks launch first
  const int h = blockIdx.y, b = blockIdx.z;
  const int tid = threadIdx.x;

  __shared__ float Qs[64][68];
  __shared__ float Ks[64][68];
  __shared__ float Ss[64][68];
  __shared__ unsigned short Vs[64][72];  // bf16 V to fit 64 KB static LDS
  __shared__ float c_arr[64], l_arr[64];

  const size_t tok0 = (size_t)b * 2048;

  // stage Q tile (64 x 64 f32)
  for (int i = tid; i < 1024; i += 256) {
    int row = i >> 4, seg = (i & 15) * 4;
    float4 v = *(const float4*)&qkv[(tok0 + qb * 64 + row) * 3072 + h * 64 + seg];
    *(float4*)&Qs[row][seg] = v;
  }

  float m_prev = -1e30f, l_prev = 0.f;
  float acc[4][4] = {};
  const int sr = tid >> 2, sseg = (tid & 3) * 16;       // softmax mapping
  const int qi0 = (tid >> 4) * 4, c0 = (tid & 15) * 4;  // S / PV mapping

  for (int kb = 0; kb <= qb; ++kb) {
    __syncthreads();
    // stage K (f32) and V (bf16) tiles
    for (int i = tid; i < 2048; i += 256) {
      int row = (i >> 4) & 63, seg = (i & 15) * 4;
      int which = i >> 10;  // 0: K, 1: V
      float4 v = *(const float4*)&qkv[(tok0 + kb * 64 + row) * 3072 + 1024 +
                                      which * 1024 + h * 64 + seg];
      if (which == 0) {
        *(float4*)&Ks[row][seg] = v;
      } else {
        ushort4 o;
        o.x = f2b(v.x); o.y = f2b(v.y); o.z = f2b(v.z); o.w = f2b(v.w);
        *(ushort4*)&Vs[row][seg] = o;
      }
    }
    __syncthreads();

    // S = Q K^T * scale (+ causal mask), 4x4 per thread
    float sacc[4][4] = {};
    for (int d4 = 0; d4 < 64; d4 += 4) {
      float4 qv[4], kv[4];
#pragma unroll
      for (int i = 0; i < 4; ++i) qv[i] = *(const float4*)&Qs[qi0 + i][d4];
#pragma unroll
      for (int j = 0; j < 4; ++j) kv[j] = *(const float4*)&Ks[c0 + j][d4];
#pragma unroll
      for (int i = 0; i < 4; ++i)
#pragma unroll
        for (int j = 0; j < 4; ++j)
          sacc[i][j] += qv[i].x * kv[j].x + qv[i].y * kv[j].y +
                        qv[i].z * kv[j].z + qv[i].w * kv[j].w;
    }
#pragma unroll
    for (int i = 0; i < 4; ++i) {
      float4 o;
      float* po = (float*)&o;
#pragma unroll
      for (int j = 0; j < 4; ++j) {
        float v = sacc[i][j] * 0.125f;
        if (kb * 64 + c0 + j > qb * 64 + qi0 + i) v = -1e30f;
        po[j] = v;
      }
      *(float4*)&Ss[qi0 + i][c0] = o;
    }
    __syncthreads();

    // online softmax, 4 threads per row
    float4 r[4];
#pragma unroll
    for (int j = 0; j < 4; ++j) r[j] = *(const float4*)&Ss[sr][sseg + j * 4];
    float mx = -1e30f;
#pragma unroll
    for (int j = 0; j < 4; ++j) {
      float* pr = (float*)&r[j];
      mx = fmaxf(mx, fmaxf(fmaxf(pr[0], pr[1]), fmaxf(pr[2], pr[3])));
    }
    mx = fmaxf(mx, __shfl_xor(mx, 1));
    mx = fmaxf(mx, __shfl_xor(mx, 2));
    float m_new = fmaxf(m_prev, mx);
    float psum = 0.f;
#pragma unroll
    for (int j = 0; j < 4; ++j) {
      float* pr = (float*)&r[j];
#pragma unroll
      for (int e = 0; e < 4; ++e) {
        float p = __expf(pr[e] - m_new);
        pr[e] = p;
        psum += p;
      }
      *(float4*)&Ss[sr][sseg + j * 4] = r[j];
    }
    psum += __shfl_xor(psum, 1);
    psum += __shfl_xor(psum, 2);
    float cf = __expf(m_prev - m_new);
    l_prev = l_prev * cf + psum;
    m_prev = m_new;
    if ((tid & 3) == 0) { c_arr[sr] = cf; l_arr[sr] = l_prev; }
    __syncthreads();

    // O = O*c + P V, 4x4 per thread
#pragma unroll
    for (int i = 0; i < 4; ++i) {
      float cfi = c_arr[qi0 + i];
#pragma unroll
      for (int j = 0; j < 4; ++j) acc[i][j] *= cfi;
    }
    for (int kc = 0; kc < 64; ++kc) {
      ushort4 vu = *(const ushort4*)&Vs[kc][c0];
      float v0 = b2f(vu.x), v1 = b2f(vu.y), v2 = b2f(vu.z), v3 = b2f(vu.w);
#pragma unroll
      for (int i = 0; i < 4; ++i) {
        float p = Ss[qi0 + i][kc];
        acc[i][0] += p * v0; acc[i][1] += p * v1;
        acc[i][2] += p * v2; acc[i][3] += p * v3;
      }
    }
  }

  // epilogue: normalize by l, write bf16
#pragma unroll
  for (int i = 0; i < 4; ++i) {
    float inv = 1.f / l_arr[qi0 + i];
    ushort4 o;
    o.x = f2b(acc[i][0] * inv); o.y = f2b(acc[i][1] * inv);
    o.z = f2b(acc[i][2] * inv); o.w = f2b(acc[i][3] * inv);
    *(ushort4*)&attnb[(tok0 + qb * 64 + qi0 + i) * 1024 + h * 64 + c0] = o;
  }
}

// ---------------------------------------------------------------------------
extern "C" void kernel_launch(void* const* d_in, const int* in_sizes, int n_in,
                              void* d_out, int out_size, void* d_ws, size_t ws_size,
                              hipStream_t stream) {
  const float* x     = (const float*)d_in[0];  // [2,2048,1024]
  const float* w_qkv = (const float*)d_in[1];  // [1024,3072]
  const float* w_out = (const float*)d_in[2];  // [1024,1024]
  const float* freqs = (const float*)d_in[3];  // [2048,64]
  float* out = (float*)d_out;                  // [2,2048,1024]

  char* ws = (char*)d_ws;
  float* qkv            = (float*)(ws);                   // 4096*3072*4 = 50331648
  unsigned short* xb    = (unsigned short*)(ws + 50331648);  // 4096*1024*2
  unsigned short* wqT   = (unsigned short*)(ws + 58720256);  // 3072*1024*2
  unsigned short* woT   = (unsigned short*)(ws + 65011712);  // 1024*1024*2
  unsigned short* attnb = (unsigned short*)(ws + 67108864);  // 4096*1024*2
  // total ws use: 75497472 bytes

  convert_bf16<<<4096, 256, 0, stream>>>(x, xb, 4096 * 1024);
  transpose_f32_bf16<<<dim3(96, 32), 256, 0, stream>>>(w_qkv, wqT, 1024, 3072);
  transpose_f32_bf16<<<dim3(32, 32), 256, 0, stream>>>(w_out, woT, 1024, 1024);
  gemm_bf16_bt<<<dim3(24, 32), 256, 0, stream>>>(xb, wqT, qkv, 4096, 3072, 1024);
  rope_kernel<<<8192, 256, 0, stream>>>(qkv, freqs);
  attn_kernel<<<dim3(32, 16, 2), 256, 0, stream>>>(qkv, attnb);
  gemm_bf16_bt<<<dim3(8, 32), 256, 0, stream>>>(attnb, woT, out, 4096, 1024, 1024);
}

// Round 2
// 209.384 us; speedup vs baseline: 4.0653x; 4.0653x over previous
//
#include <hip/hip_runtime.h>

// ---------------------------------------------------------------------------
// Fused attention block: qkv GEMM -> RoPE -> causal SDPA (MFMA) -> out GEMM
// B=2 S=2048 D=1024 H=16 DH=64. bf16 MFMA everywhere.
// MFMA fragment mapping (verified round 1): A row=lane&15, k=oct*8+e;
// B(from row-major "BT"): col=lane&15, k=oct*8+e; C/D row=oct*4+r, col=lane&15.
// ---------------------------------------------------------------------------

typedef __bf16 bf16x8 __attribute__((ext_vector_type(8)));
typedef float f32x4 __attribute__((ext_vector_type(4)));

__device__ __forceinline__ unsigned short f2b(float f) {
  unsigned int u = __builtin_bit_cast(unsigned int, f);
  unsigned int lsb = (u >> 16) & 1u;
  u += 0x7fffu + lsb;  // round-to-nearest-even
  return (unsigned short)(u >> 16);
}
__device__ __forceinline__ float b2f(unsigned short h) {
  unsigned int u = ((unsigned int)h) << 16;
  return __builtin_bit_cast(float, u);
}
__device__ __forceinline__ unsigned int pk2(float a, float b) {
  return (unsigned int)f2b(a) | ((unsigned int)f2b(b) << 16);
}
__device__ __forceinline__ void unp8(uint4 v, float* f) {
  unsigned int u[4] = {v.x, v.y, v.z, v.w};
#pragma unroll
  for (int i = 0; i < 4; ++i) {
    f[2 * i] = b2f((unsigned short)(u[i] & 0xffff));
    f[2 * i + 1] = b2f((unsigned short)(u[i] >> 16));
  }
}

// -------------------- transpose [K][N] f32 -> [N][K] bf16 -------------------
__global__ __launch_bounds__(256) void transpose_f32_bf16(const float* __restrict__ src,
                                                          unsigned short* __restrict__ dst,
                                                          int K, int N) {
  __shared__ float tile[32][33];
  int n0 = blockIdx.x * 32, k0 = blockIdx.y * 32;
  int c = threadIdx.x & 31, r4 = threadIdx.x >> 5;
#pragma unroll
  for (int p = 0; p < 4; ++p) {
    int r = r4 + p * 8;
    tile[r][c] = src[(size_t)(k0 + r) * N + n0 + c];
  }
  __syncthreads();
#pragma unroll
  for (int p = 0; p < 4; ++p) {
    int r = r4 + p * 8;
    dst[(size_t)(n0 + r) * K + k0 + c] = f2b(tile[c][r]);
  }
}

// --------------------------- bf16 MFMA GEMM --------------------------------
// C[M][N] = A[M][K] * B, B given as BT[N][K] bf16. A either f32 (converted
// during staging) or bf16. C either f32 or bf16.
template <int A_F32, int C_BF16>
__global__ __launch_bounds__(256) void gemm_bt(const void* __restrict__ Ap,
                                               const unsigned short* __restrict__ BT,
                                               void* __restrict__ Cp,
                                               int M, int N, int K) {
  __shared__ unsigned short As[128][40];
  __shared__ unsigned short Bs[128][40];
  const int tid = threadIdx.x;
  const int m0 = blockIdx.y * 128, n0 = blockIdx.x * 128;
  const int lane = tid & 63, wid = tid >> 6;
  const int wm = (wid >> 1) * 64, wn = (wid & 1) * 64;
  const int fr = lane & 15, oct = lane >> 4;

  f32x4 acc[4][4] = {};

  for (int k0 = 0; k0 < K; k0 += 32) {
    __syncthreads();
#pragma unroll
    for (int p = 0; p < 2; ++p) {
      int i = p * 256 + tid;
      int row = i >> 2, kc = (i & 3) * 8;
      if (A_F32) {
        const float* A = (const float*)Ap;
        float4 a0 = *(const float4*)&A[(size_t)(m0 + row) * K + k0 + kc];
        float4 a1 = *(const float4*)&A[(size_t)(m0 + row) * K + k0 + kc + 4];
        uint4 w;
        w.x = pk2(a0.x, a0.y); w.y = pk2(a0.z, a0.w);
        w.z = pk2(a1.x, a1.y); w.w = pk2(a1.z, a1.w);
        *(uint4*)&As[row][kc] = w;
      } else {
        const unsigned short* A = (const unsigned short*)Ap;
        *(uint4*)&As[row][kc] = *(const uint4*)&A[(size_t)(m0 + row) * K + k0 + kc];
      }
      *(uint4*)&Bs[row][kc] = *(const uint4*)&BT[(size_t)(n0 + row) * K + k0 + kc];
    }
    __syncthreads();
    bf16x8 af[4], bq[4];
#pragma unroll
    for (int i = 0; i < 4; ++i)
      af[i] = __builtin_bit_cast(bf16x8, *(const uint4*)&As[wm + i * 16 + fr][oct * 8]);
#pragma unroll
    for (int j = 0; j < 4; ++j)
      bq[j] = __builtin_bit_cast(bf16x8, *(const uint4*)&Bs[wn + j * 16 + fr][oct * 8]);
#pragma unroll
    for (int i = 0; i < 4; ++i)
#pragma unroll
      for (int j = 0; j < 4; ++j)
        acc[i][j] = __builtin_amdgcn_mfma_f32_16x16x32_bf16(af[i], bq[j], acc[i][j], 0, 0, 0);
  }

#pragma unroll
  for (int i = 0; i < 4; ++i)
#pragma unroll
    for (int j = 0; j < 4; ++j)
#pragma unroll
      for (int r = 0; r < 4; ++r) {
        size_t idx = (size_t)(m0 + wm + i * 16 + oct * 4 + r) * N + n0 + wn + j * 16 + fr;
        if (C_BF16)
          ((unsigned short*)Cp)[idx] = f2b(acc[i][j][r]);
        else
          ((float*)Cp)[idx] = acc[i][j][r];
      }
}

// ----------------- prep: RoPE + layout (Q,K rows; V transposed) -------------
// qkvb [4096][3072] bf16. Writes Qb,Kb [b*16+h][2048][64] bf16 (Q scaled by
// 1/8), Vtg [b*16+h][64][2048] bf16 (transposed).
__global__ __launch_bounds__(256) void prep_kernel(const unsigned short* __restrict__ qkvb,
                                                   const float* __restrict__ freqs,
                                                   unsigned short* __restrict__ Qb,
                                                   unsigned short* __restrict__ Kb,
                                                   unsigned short* __restrict__ Vtg) {
  const int sb = blockIdx.x, h = blockIdx.y, b = blockIdx.z;
  const int tid = threadIdx.x;
  __shared__ float Vs[64][65];
  const int sl = tid >> 2, c8 = (tid & 3) * 8;
  const int s = sb * 64 + sl;
  const size_t tok = (size_t)(b * 2048 + s);
  const unsigned short* row = qkvb + tok * 3072 + h * 64;

  float cl[8], snl[8], ch[8], snh[8];
#pragma unroll
  for (int e = 0; e < 8; ++e) {
    float fl = freqs[s * 64 + c8 + e];
    float fh = freqs[s * 64 + 32 + c8 + e];
    cl[e] = cosf(fl); snl[e] = sinf(fl);
    ch[e] = cosf(fh); snh[e] = sinf(fh);
  }
  const size_t obase = ((size_t)(b * 16 + h) * 2048 + s) * 64;

  // Q (scaled by 0.125)
  {
    float lo[8], hi[8];
    unp8(*(const uint4*)(row + c8), lo);
    unp8(*(const uint4*)(row + 32 + c8), hi);
    float olo[8], ohi[8];
#pragma unroll
    for (int e = 0; e < 8; ++e) {
      olo[e] = (lo[e] * cl[e] - hi[e] * snl[e]) * 0.125f;
      ohi[e] = (hi[e] * ch[e] + lo[e] * snh[e]) * 0.125f;
    }
    uint4 w0, w1;
    w0.x = pk2(olo[0], olo[1]); w0.y = pk2(olo[2], olo[3]);
    w0.z = pk2(olo[4], olo[5]); w0.w = pk2(olo[6], olo[7]);
    w1.x = pk2(ohi[0], ohi[1]); w1.y = pk2(ohi[2], ohi[3]);
    w1.z = pk2(ohi[4], ohi[5]); w1.w = pk2(ohi[6], ohi[7]);
    *(uint4*)(Qb + obase + c8) = w0;
    *(uint4*)(Qb + obase + 32 + c8) = w1;
  }
  // K
  {
    float lo[8], hi[8];
    unp8(*(const uint4*)(row + 1024 + c8), lo);
    unp8(*(const uint4*)(row + 1024 + 32 + c8), hi);
    float olo[8], ohi[8];
#pragma unroll
    for (int e = 0; e < 8; ++e) {
      olo[e] = lo[e] * cl[e] - hi[e] * snl[e];
      ohi[e] = hi[e] * ch[e] + lo[e] * snh[e];
    }
    uint4 w0, w1;
    w0.x = pk2(olo[0], olo[1]); w0.y = pk2(olo[2], olo[3]);
    w0.z = pk2(olo[4], olo[5]); w0.w = pk2(olo[6], olo[7]);
    w1.x = pk2(ohi[0], ohi[1]); w1.y = pk2(ohi[2], ohi[3]);
    w1.z = pk2(ohi[4], ohi[5]); w1.w = pk2(ohi[6], ohi[7]);
    *(uint4*)(Kb + obase + c8) = w0;
    *(uint4*)(Kb + obase + 32 + c8) = w1;
  }
  // V -> LDS f32, then transposed bf16 out
  {
    float lo[8], hi[8];
    unp8(*(const uint4*)(row + 2048 + c8), lo);
    unp8(*(const uint4*)(row + 2048 + 32 + c8), hi);
#pragma unroll
    for (int e = 0; e < 8; ++e) {
      Vs[sl][c8 + e] = lo[e];
      Vs[sl][32 + c8 + e] = hi[e];
    }
  }
  __syncthreads();
  {
    const int d = tid >> 2, sc0 = (tid & 3) * 16;
    const size_t vbase = ((size_t)(b * 16 + h) * 64 + d) * 2048 + sb * 64 + sc0;
#pragma unroll
    for (int g = 0; g < 4; ++g) {
      ushort4 u;
      u.x = f2b(Vs[sc0 + g * 4 + 0][d]);
      u.y = f2b(Vs[sc0 + g * 4 + 1][d]);
      u.z = f2b(Vs[sc0 + g * 4 + 2][d]);
      u.w = f2b(Vs[sc0 + g * 4 + 3][d]);
      *(ushort4*)(Vtg + vbase + g * 4) = u;
    }
  }
}

// --------------------------- MFMA flash attention ---------------------------
// Block = (qb, h, b), 256 threads = 4 waves; wave w owns q-rows w*16..w*16+15.
// Q fragments hoisted in registers; K and V^T staged in LDS per 64-wide
// KV tile; P via per-wave LDS round-trip (C-layout write, A-layout read).
__global__ __launch_bounds__(256) void attn_mfma(const unsigned short* __restrict__ Qb,
                                                 const unsigned short* __restrict__ Kb,
                                                 const unsigned short* __restrict__ Vtg,
                                                 unsigned short* __restrict__ attnb) {
  const int qb = 31 - blockIdx.x;  // heavy blocks first
  const int h = blockIdx.y, b = blockIdx.z;
  const int tid = threadIdx.x, lane = tid & 63, w = tid >> 6;
  const int fr = lane & 15, oct = lane >> 4;

  __shared__ unsigned short Ks[64][72];
  __shared__ unsigned short Vt[64][72];
  __shared__ unsigned short Pl[4][16][72];

  const size_t bh = (size_t)(b * 16 + h);
  const unsigned short* Qp = Qb + (bh * 2048 + qb * 64 + w * 16 + fr) * 64;
  const bf16x8 qf0 = __builtin_bit_cast(bf16x8, *(const uint4*)(Qp + oct * 8));
  const bf16x8 qf1 = __builtin_bit_cast(bf16x8, *(const uint4*)(Qp + 32 + oct * 8));

  float m_prev[4], l_prev[4];
#pragma unroll
  for (int r = 0; r < 4; ++r) { m_prev[r] = -1e30f; l_prev[r] = 0.f; }
  f32x4 acc[4] = {};  // acc[t2][r] = O[q=w*16+oct*4+r][d=t2*16+fr]

  const int sk = tid >> 2, sc = (tid & 3) * 16;
  const unsigned short* Kp = Kb + bh * 2048 * 64;
  const unsigned short* Vp = Vtg + bh * 64 * 2048;

  for (int kb = 0; kb <= qb; ++kb) {
    __syncthreads();
    {
      const unsigned short* ks = Kp + (size_t)(kb * 64 + sk) * 64 + sc;
      uint4 k0 = *(const uint4*)ks, k1 = *(const uint4*)(ks + 8);
      const unsigned short* vs = Vp + (size_t)sk * 2048 + kb * 64 + sc;
      uint4 v0 = *(const uint4*)vs, v1 = *(const uint4*)(vs + 8);
      *(uint4*)&Ks[sk][sc] = k0;
      *(uint4*)&Ks[sk][sc + 8] = k1;
      *(uint4*)&Vt[sk][sc] = v0;
      *(uint4*)&Vt[sk][sc + 8] = v1;
    }
    __syncthreads();

    // S = (Q/8) K^T  : s4[t][r] = S[q=w*16+oct*4+r][k=kb*64+t*16+fr]
    f32x4 s4[4] = {};
#pragma unroll
    for (int t = 0; t < 4; ++t) {
      bf16x8 b0 = __builtin_bit_cast(bf16x8, *(const uint4*)&Ks[t * 16 + fr][oct * 8]);
      s4[t] = __builtin_amdgcn_mfma_f32_16x16x32_bf16(qf0, b0, s4[t], 0, 0, 0);
      bf16x8 b1 = __builtin_bit_cast(bf16x8, *(const uint4*)&Ks[t * 16 + fr][32 + oct * 8]);
      s4[t] = __builtin_amdgcn_mfma_f32_16x16x32_bf16(qf1, b1, s4[t], 0, 0, 0);
    }
    if (kb == qb) {  // causal mask on the diagonal tile
#pragma unroll
      for (int t = 0; t < 4; ++t)
#pragma unroll
        for (int r = 0; r < 4; ++r)
          if (t * 16 + fr > w * 16 + oct * 4 + r) s4[t][r] = -1e30f;
    }

    // online softmax (rows replicated across the 16 fr-lanes of each oct)
    float mnew[4], cf[4], psum[4];
#pragma unroll
    for (int r = 0; r < 4; ++r) {
      float pm = fmaxf(fmaxf(s4[0][r], s4[1][r]), fmaxf(s4[2][r], s4[3][r]));
      pm = fmaxf(pm, __shfl_xor(pm, 1));
      pm = fmaxf(pm, __shfl_xor(pm, 2));
      pm = fmaxf(pm, __shfl_xor(pm, 4));
      pm = fmaxf(pm, __shfl_xor(pm, 8));
      mnew[r] = fmaxf(m_prev[r], pm);
      cf[r] = __expf(m_prev[r] - mnew[r]);
      m_prev[r] = mnew[r];
      psum[r] = 0.f;
    }
#pragma unroll
    for (int t = 0; t < 4; ++t)
#pragma unroll
      for (int r = 0; r < 4; ++r) {
        float p = __expf(s4[t][r] - mnew[r]);
        s4[t][r] = p;
        psum[r] += p;
      }
#pragma unroll
    for (int r = 0; r < 4; ++r) {
      float ps = psum[r];
      ps += __shfl_xor(ps, 1);
      ps += __shfl_xor(ps, 2);
      ps += __shfl_xor(ps, 4);
      ps += __shfl_xor(ps, 8);
      l_prev[r] = l_prev[r] * cf[r] + ps;
    }

    // P -> LDS (C-layout write), rescale O, read back as A fragments
#pragma unroll
    for (int t = 0; t < 4; ++t)
#pragma unroll
      for (int r = 0; r < 4; ++r)
        Pl[w][oct * 4 + r][t * 16 + fr] = f2b(s4[t][r]);
#pragma unroll
    for (int t2 = 0; t2 < 4; ++t2)
#pragma unroll
      for (int r = 0; r < 4; ++r) acc[t2][r] *= cf[r];

    const bf16x8 pf0 = __builtin_bit_cast(bf16x8, *(const uint4*)&Pl[w][fr][oct * 8]);
    const bf16x8 pf1 = __builtin_bit_cast(bf16x8, *(const uint4*)&Pl[w][fr][32 + oct * 8]);
#pragma unroll
    for (int t2 = 0; t2 < 4; ++t2) {
      bf16x8 v0 = __builtin_bit_cast(bf16x8, *(const uint4*)&Vt[t2 * 16 + fr][oct * 8]);
      acc[t2] = __builtin_amdgcn_mfma_f32_16x16x32_bf16(pf0, v0, acc[t2], 0, 0, 0);
      bf16x8 v1 = __builtin_bit_cast(bf16x8, *(const uint4*)&Vt[t2 * 16 + fr][32 + oct * 8]);
      acc[t2] = __builtin_amdgcn_mfma_f32_16x16x32_bf16(pf1, v1, acc[t2], 0, 0, 0);
    }
  }

  // epilogue: normalize, write bf16
#pragma unroll
  for (int r = 0; r < 4; ++r) {
    float inv = 1.f / l_prev[r];
    size_t orow = (size_t)(b * 2048 + qb * 64 + w * 16 + oct * 4 + r);
#pragma unroll
    for (int t2 = 0; t2 < 4; ++t2)
      attnb[orow * 1024 + h * 64 + t2 * 16 + fr] = f2b(acc[t2][r] * inv);
  }
}

// ---------------------------------------------------------------------------
extern "C" void kernel_launch(void* const* d_in, const int* in_sizes, int n_in,
                              void* d_out, int out_size, void* d_ws, size_t ws_size,
                              hipStream_t stream) {
  const float* x     = (const float*)d_in[0];  // [2,2048,1024]
  const float* w_qkv = (const float*)d_in[1];  // [1024,3072]
  const float* w_out = (const float*)d_in[2];  // [1024,1024]
  const float* freqs = (const float*)d_in[3];  // [2048,64]
  float* out = (float*)d_out;

  char* ws = (char*)d_ws;
  unsigned short* qkvb = (unsigned short*)(ws);             // 4096*3072*2 = 25165824
  unsigned short* Qb   = (unsigned short*)(ws + 25165824);  // 8388608
  unsigned short* Kb   = (unsigned short*)(ws + 33554432);  // 8388608
  unsigned short* Vtg  = (unsigned short*)(ws + 41943040);  // 8388608
  unsigned short* attnb= (unsigned short*)(ws + 50331648);  // 8388608
  unsigned short* wqT  = (unsigned short*)(ws + 58720256);  // 6291456
  unsigned short* woT  = (unsigned short*)(ws + 65011712);  // 2097152
  // total ws use: 67108864 bytes (64 MiB)

  transpose_f32_bf16<<<dim3(96, 32), 256, 0, stream>>>(w_qkv, wqT, 1024, 3072);
  transpose_f32_bf16<<<dim3(32, 32), 256, 0, stream>>>(w_out, woT, 1024, 1024);
  gemm_bt<1, 1><<<dim3(24, 32), 256, 0, stream>>>(x, wqT, qkvb, 4096, 3072, 1024);
  prep_kernel<<<dim3(32, 16, 2), 256, 0, stream>>>(qkvb, freqs, Qb, Kb, Vtg);
  attn_mfma<<<dim3(32, 16, 2), 256, 0, stream>>>(Qb, Kb, Vtg, attnb);
  gemm_bt<0, 0><<<dim3(8, 32), 256, 0, stream>>>(attnb, woT, out, 4096, 1024, 1024);
}

// Round 3
// 161.539 us; speedup vs baseline: 5.2694x; 1.2962x over previous
//
#include <hip/hip_runtime.h>

// ---------------------------------------------------------------------------
// Fused attention block: qkv GEMM -> RoPE -> causal SDPA (MFMA) -> out GEMM
// B=2 S=2048 D=1024 H=16 DH=64. bf16 MFMA everywhere.
// MFMA fragment mapping (verified round 1/2): A/B-frag outer=lane&15,
// k=oct*8+e; C/D row=oct*4+r, col=lane&15.
// Attention: paired q-tiles (i, 31-i) per block for uniform work; swapped
// QK^T (S^T = mfma(K,Q)) so softmax is per-lane-column (2 shfl per reduce).
// ---------------------------------------------------------------------------

typedef __bf16 bf16x8 __attribute__((ext_vector_type(8)));
typedef float f32x4 __attribute__((ext_vector_type(4)));

__device__ __forceinline__ unsigned short f2b(float f) {
  unsigned int u = __builtin_bit_cast(unsigned int, f);
  unsigned int lsb = (u >> 16) & 1u;
  u += 0x7fffu + lsb;  // round-to-nearest-even
  return (unsigned short)(u >> 16);
}
__device__ __forceinline__ float b2f(unsigned short h) {
  unsigned int u = ((unsigned int)h) << 16;
  return __builtin_bit_cast(float, u);
}
__device__ __forceinline__ unsigned int pk2(float a, float b) {
  return (unsigned int)f2b(a) | ((unsigned int)f2b(b) << 16);
}
__device__ __forceinline__ void unp8(uint4 v, float* f) {
  unsigned int u[4] = {v.x, v.y, v.z, v.w};
#pragma unroll
  for (int i = 0; i < 4; ++i) {
    f[2 * i] = b2f((unsigned short)(u[i] & 0xffff));
    f[2 * i + 1] = b2f((unsigned short)(u[i] >> 16));
  }
}

// -------------------- transpose [K][N] f32 -> [N][K] bf16 -------------------
__global__ __launch_bounds__(256) void transpose_f32_bf16(const float* __restrict__ src,
                                                          unsigned short* __restrict__ dst,
                                                          int K, int N) {
  __shared__ float tile[32][33];
  int n0 = blockIdx.x * 32, k0 = blockIdx.y * 32;
  int c = threadIdx.x & 31, r4 = threadIdx.x >> 5;
#pragma unroll
  for (int p = 0; p < 4; ++p) {
    int r = r4 + p * 8;
    tile[r][c] = src[(size_t)(k0 + r) * N + n0 + c];
  }
  __syncthreads();
#pragma unroll
  for (int p = 0; p < 4; ++p) {
    int r = r4 + p * 8;
    dst[(size_t)(n0 + r) * K + k0 + c] = f2b(tile[c][r]);
  }
}

// --------------------------- bf16 MFMA GEMM --------------------------------
// C[M][N] = A[M][K] * B, B given as BT[N][K] bf16. A either f32 (converted
// during staging) or bf16. C either f32 or bf16.
template <int A_F32, int C_BF16>
__global__ __launch_bounds__(256) void gemm_bt(const void* __restrict__ Ap,
                                               const unsigned short* __restrict__ BT,
                                               void* __restrict__ Cp,
                                               int M, int N, int K) {
  __shared__ unsigned short As[128][40];
  __shared__ unsigned short Bs[128][40];
  const int tid = threadIdx.x;
  const int m0 = blockIdx.y * 128, n0 = blockIdx.x * 128;
  const int lane = tid & 63, wid = tid >> 6;
  const int wm = (wid >> 1) * 64, wn = (wid & 1) * 64;
  const int fr = lane & 15, oct = lane >> 4;

  f32x4 acc[4][4] = {};

  for (int k0 = 0; k0 < K; k0 += 32) {
    __syncthreads();
#pragma unroll
    for (int p = 0; p < 2; ++p) {
      int i = p * 256 + tid;
      int row = i >> 2, kc = (i & 3) * 8;
      if (A_F32) {
        const float* A = (const float*)Ap;
        float4 a0 = *(const float4*)&A[(size_t)(m0 + row) * K + k0 + kc];
        float4 a1 = *(const float4*)&A[(size_t)(m0 + row) * K + k0 + kc + 4];
        uint4 w;
        w.x = pk2(a0.x, a0.y); w.y = pk2(a0.z, a0.w);
        w.z = pk2(a1.x, a1.y); w.w = pk2(a1.z, a1.w);
        *(uint4*)&As[row][kc] = w;
      } else {
        const unsigned short* A = (const unsigned short*)Ap;
        *(uint4*)&As[row][kc] = *(const uint4*)&A[(size_t)(m0 + row) * K + k0 + kc];
      }
      *(uint4*)&Bs[row][kc] = *(const uint4*)&BT[(size_t)(n0 + row) * K + k0 + kc];
    }
    __syncthreads();
    bf16x8 af[4], bq[4];
#pragma unroll
    for (int i = 0; i < 4; ++i)
      af[i] = __builtin_bit_cast(bf16x8, *(const uint4*)&As[wm + i * 16 + fr][oct * 8]);
#pragma unroll
    for (int j = 0; j < 4; ++j)
      bq[j] = __builtin_bit_cast(bf16x8, *(const uint4*)&Bs[wn + j * 16 + fr][oct * 8]);
#pragma unroll
    for (int i = 0; i < 4; ++i)
#pragma unroll
      for (int j = 0; j < 4; ++j)
        acc[i][j] = __builtin_amdgcn_mfma_f32_16x16x32_bf16(af[i], bq[j], acc[i][j], 0, 0, 0);
  }

#pragma unroll
  for (int i = 0; i < 4; ++i)
#pragma unroll
    for (int j = 0; j < 4; ++j)
#pragma unroll
      for (int r = 0; r < 4; ++r) {
        size_t idx = (size_t)(m0 + wm + i * 16 + oct * 4 + r) * N + n0 + wn + j * 16 + fr;
        if (C_BF16)
          ((unsigned short*)Cp)[idx] = f2b(acc[i][j][r]);
        else
          ((float*)Cp)[idx] = acc[i][j][r];
      }
}

// ----------------- prep: RoPE + layout (Q,K rows; V transposed) -------------
// qkvb [4096][3072] bf16. Writes Qb,Kb [b*16+h][2048][64] bf16 (Q scaled by
// 1/8), Vtg [b*16+h][64][2048] bf16 (transposed).
__global__ __launch_bounds__(256) void prep_kernel(const unsigned short* __restrict__ qkvb,
                                                   const float* __restrict__ freqs,
                                                   unsigned short* __restrict__ Qb,
                                                   unsigned short* __restrict__ Kb,
                                                   unsigned short* __restrict__ Vtg) {
  const int sb = blockIdx.x, h = blockIdx.y, b = blockIdx.z;
  const int tid = threadIdx.x;
  __shared__ float Vs[64][65];
  const int sl = tid >> 2, c8 = (tid & 3) * 8;
  const int s = sb * 64 + sl;
  const size_t tok = (size_t)(b * 2048 + s);
  const unsigned short* row = qkvb + tok * 3072 + h * 64;

  float cl[8], snl[8], ch[8], snh[8];
#pragma unroll
  for (int e = 0; e < 8; ++e) {
    float fl = freqs[s * 64 + c8 + e];
    float fh = freqs[s * 64 + 32 + c8 + e];
    cl[e] = cosf(fl); snl[e] = sinf(fl);
    ch[e] = cosf(fh); snh[e] = sinf(fh);
  }
  const size_t obase = ((size_t)(b * 16 + h) * 2048 + s) * 64;

  // Q (scaled by 0.125)
  {
    float lo[8], hi[8];
    unp8(*(const uint4*)(row + c8), lo);
    unp8(*(const uint4*)(row + 32 + c8), hi);
    float olo[8], ohi[8];
#pragma unroll
    for (int e = 0; e < 8; ++e) {
      olo[e] = (lo[e] * cl[e] - hi[e] * snl[e]) * 0.125f;
      ohi[e] = (hi[e] * ch[e] + lo[e] * snh[e]) * 0.125f;
    }
    uint4 w0, w1;
    w0.x = pk2(olo[0], olo[1]); w0.y = pk2(olo[2], olo[3]);
    w0.z = pk2(olo[4], olo[5]); w0.w = pk2(olo[6], olo[7]);
    w1.x = pk2(ohi[0], ohi[1]); w1.y = pk2(ohi[2], ohi[3]);
    w1.z = pk2(ohi[4], ohi[5]); w1.w = pk2(ohi[6], ohi[7]);
    *(uint4*)(Qb + obase + c8) = w0;
    *(uint4*)(Qb + obase + 32 + c8) = w1;
  }
  // K
  {
    float lo[8], hi[8];
    unp8(*(const uint4*)(row + 1024 + c8), lo);
    unp8(*(const uint4*)(row + 1024 + 32 + c8), hi);
    float olo[8], ohi[8];
#pragma unroll
    for (int e = 0; e < 8; ++e) {
      olo[e] = lo[e] * cl[e] - hi[e] * snl[e];
      ohi[e] = hi[e] * ch[e] + lo[e] * snh[e];
    }
    uint4 w0, w1;
    w0.x = pk2(olo[0], olo[1]); w0.y = pk2(olo[2], olo[3]);
    w0.z = pk2(olo[4], olo[5]); w0.w = pk2(olo[6], olo[7]);
    w1.x = pk2(ohi[0], ohi[1]); w1.y = pk2(ohi[2], ohi[3]);
    w1.z = pk2(ohi[4], ohi[5]); w1.w = pk2(ohi[6], ohi[7]);
    *(uint4*)(Kb + obase + c8) = w0;
    *(uint4*)(Kb + obase + 32 + c8) = w1;
  }
  // V -> LDS f32, then transposed bf16 out
  {
    float lo[8], hi[8];
    unp8(*(const uint4*)(row + 2048 + c8), lo);
    unp8(*(const uint4*)(row + 2048 + 32 + c8), hi);
#pragma unroll
    for (int e = 0; e < 8; ++e) {
      Vs[sl][c8 + e] = lo[e];
      Vs[sl][32 + c8 + e] = hi[e];
    }
  }
  __syncthreads();
  {
    const int d = tid >> 2, sc0 = (tid & 3) * 16;
    const size_t vbase = ((size_t)(b * 16 + h) * 64 + d) * 2048 + sb * 64 + sc0;
#pragma unroll
    for (int g = 0; g < 4; ++g) {
      ushort4 u;
      u.x = f2b(Vs[sc0 + g * 4 + 0][d]);
      u.y = f2b(Vs[sc0 + g * 4 + 1][d]);
      u.z = f2b(Vs[sc0 + g * 4 + 2][d]);
      u.w = f2b(Vs[sc0 + g * 4 + 3][d]);
      *(ushort4*)(Vtg + vbase + g * 4) = u;
    }
  }
}

// --------------------------- MFMA flash attention ---------------------------
// Block = (pair, h, b): q-tiles {pair, 31-pair} (64 rows each) -> uniform 33
// MFMA-iterations per block. 256 threads = 4 waves; wave w owns rows
// w*16..w*16+15 of each tile. Swapped QK^T: S^T = mfma(K,Q) so each lane
// holds one q-column; softmax reduce = 2 shfl. P via per-wave LDS b64 writes.
__global__ __launch_bounds__(256) void attn_mfma(const unsigned short* __restrict__ Qb,
                                                 const unsigned short* __restrict__ Kb,
                                                 const unsigned short* __restrict__ Vtg,
                                                 unsigned short* __restrict__ attnb) {
  const int h = blockIdx.y, b = blockIdx.z;
  const int qt0 = blockIdx.x;   // 0..15
  const int qt1 = 31 - qt0;     // 16..31
  const int tid = threadIdx.x, lane = tid & 63, w = tid >> 6;
  const int fr = lane & 15, oct = lane >> 4;

  __shared__ unsigned short Ks[64][72];
  __shared__ unsigned short Vt[64][72];
  __shared__ unsigned short Pl[4][2][16][72];

  const size_t bh = (size_t)(b * 16 + h);
  const int qtv[2] = {qt0, qt1};

  bf16x8 qf[2][2];
#pragma unroll
  for (int tl = 0; tl < 2; ++tl) {
    const unsigned short* Qp = Qb + (bh * 2048 + qtv[tl] * 64 + w * 16 + fr) * 64;
    qf[tl][0] = __builtin_bit_cast(bf16x8, *(const uint4*)(Qp + oct * 8));
    qf[tl][1] = __builtin_bit_cast(bf16x8, *(const uint4*)(Qp + 32 + oct * 8));
  }

  float m_prev[2] = {-1e30f, -1e30f};
  float l_prev[2] = {0.f, 0.f};
  f32x4 acc[2][4] = {};  // acc[tl][t2][r] = O[q=w*16+oct*4+r][d=t2*16+fr]

  const int sk = tid >> 2, sc = (tid & 3) * 16;
  const unsigned short* Kp = Kb + bh * 2048 * 64;
  const unsigned short* Vp = Vtg + bh * 64 * 2048;

  for (int kb = 0; kb <= qt1; ++kb) {
    __syncthreads();
    {
      const unsigned short* ks = Kp + (size_t)(kb * 64 + sk) * 64 + sc;
      uint4 k0 = *(const uint4*)ks, k1 = *(const uint4*)(ks + 8);
      const unsigned short* vs = Vp + (size_t)sk * 2048 + kb * 64 + sc;
      uint4 v0 = *(const uint4*)vs, v1 = *(const uint4*)(vs + 8);
      *(uint4*)&Ks[sk][sc] = k0;
      *(uint4*)&Ks[sk][sc + 8] = k1;
      *(uint4*)&Vt[sk][sc] = v0;
      *(uint4*)&Vt[sk][sc + 8] = v1;
    }
    __syncthreads();

    const bool doA = (kb <= qt0);

    // K fragments (shared by both q-tiles)
    bf16x8 kf0[4], kf1[4];
#pragma unroll
    for (int t = 0; t < 4; ++t) {
      kf0[t] = __builtin_bit_cast(bf16x8, *(const uint4*)&Ks[t * 16 + fr][oct * 8]);
      kf1[t] = __builtin_bit_cast(bf16x8, *(const uint4*)&Ks[t * 16 + fr][32 + oct * 8]);
    }

    // S^T: s4[tl][t][r] = S[q = qt*64+w*16+fr][k = kb*64+t*16+oct*4+r]
    f32x4 s4[2][4];
#pragma unroll
    for (int tl = 0; tl < 2; ++tl) {
      if (tl == 0 && !doA) continue;
#pragma unroll
      for (int t = 0; t < 4; ++t) {
        f32x4 s = {};
        s = __builtin_amdgcn_mfma_f32_16x16x32_bf16(kf0[t], qf[tl][0], s, 0, 0, 0);
        s = __builtin_amdgcn_mfma_f32_16x16x32_bf16(kf1[t], qf[tl][1], s, 0, 0, 0);
        s4[tl][t] = s;
      }
      if (kb == qtv[tl]) {  // diagonal tile: causal mask (k > q)
#pragma unroll
        for (int t = 0; t < 4; ++t)
#pragma unroll
          for (int r = 0; r < 4; ++r)
            if (t * 16 + oct * 4 + r > w * 16 + fr) s4[tl][t][r] = -1e30f;
      }
    }

    // online softmax per lane (q-column = fr); reduce across octs (2 shfl)
    float cfr[2][4];
#pragma unroll
    for (int tl = 0; tl < 2; ++tl) {
      if (tl == 0 && !doA) continue;
      float pm = -1e30f;
#pragma unroll
      for (int t = 0; t < 4; ++t)
#pragma unroll
        for (int r = 0; r < 4; ++r) pm = fmaxf(pm, s4[tl][t][r]);
      pm = fmaxf(pm, __shfl_xor(pm, 16));
      pm = fmaxf(pm, __shfl_xor(pm, 32));
      float mnew = fmaxf(m_prev[tl], pm);
      float cf = __expf(m_prev[tl] - mnew);
      m_prev[tl] = mnew;
      float psum = 0.f;
#pragma unroll
      for (int t = 0; t < 4; ++t) {
#pragma unroll
        for (int r = 0; r < 4; ++r) {
          float p = __expf(s4[tl][t][r] - mnew);
          s4[tl][t][r] = p;
          psum += p;
        }
        uint2 pw;
        pw.x = pk2(s4[tl][t][0], s4[tl][t][1]);
        pw.y = pk2(s4[tl][t][2], s4[tl][t][3]);
        *(uint2*)&Pl[w][tl][fr][t * 16 + oct * 4] = pw;  // P[q][k] layout
      }
      psum += __shfl_xor(psum, 16);
      psum += __shfl_xor(psum, 32);
      l_prev[tl] = l_prev[tl] * cf + psum;
#pragma unroll
      for (int r = 0; r < 4; ++r) cfr[tl][r] = __shfl(cf, oct * 4 + r);
    }

    // V fragments (shared) + PV
    bf16x8 vf0[4], vf1[4];
#pragma unroll
    for (int t2 = 0; t2 < 4; ++t2) {
      vf0[t2] = __builtin_bit_cast(bf16x8, *(const uint4*)&Vt[t2 * 16 + fr][oct * 8]);
      vf1[t2] = __builtin_bit_cast(bf16x8, *(const uint4*)&Vt[t2 * 16 + fr][32 + oct * 8]);
    }
#pragma unroll
    for (int tl = 0; tl < 2; ++tl) {
      if (tl == 0 && !doA) continue;
      const bf16x8 pf0 =
          __builtin_bit_cast(bf16x8, *(const uint4*)&Pl[w][tl][fr][oct * 8]);
      const bf16x8 pf1 =
          __builtin_bit_cast(bf16x8, *(const uint4*)&Pl[w][tl][fr][32 + oct * 8]);
#pragma unroll
      for (int t2 = 0; t2 < 4; ++t2) {
        f32x4 a = acc[tl][t2];
#pragma unroll
        for (int r = 0; r < 4; ++r) a[r] *= cfr[tl][r];
        a = __builtin_amdgcn_mfma_f32_16x16x32_bf16(pf0, vf0[t2], a, 0, 0, 0);
        a = __builtin_amdgcn_mfma_f32_16x16x32_bf16(pf1, vf1[t2], a, 0, 0, 0);
        acc[tl][t2] = a;
      }
    }
  }

  // epilogue: normalize by l (transposed via shfl), write bf16
#pragma unroll
  for (int tl = 0; tl < 2; ++tl) {
    float linv[4];
#pragma unroll
    for (int r = 0; r < 4; ++r) linv[r] = 1.f / __shfl(l_prev[tl], oct * 4 + r);
#pragma unroll
    for (int r = 0; r < 4; ++r) {
      size_t orow = (size_t)(b * 2048 + qtv[tl] * 64 + w * 16 + oct * 4 + r);
#pragma unroll
      for (int t2 = 0; t2 < 4; ++t2)
        attnb[orow * 1024 + h * 64 + t2 * 16 + fr] = f2b(acc[tl][t2][r] * linv[r]);
    }
  }
}

// ---------------------------------------------------------------------------
extern "C" void kernel_launch(void* const* d_in, const int* in_sizes, int n_in,
                              void* d_out, int out_size, void* d_ws, size_t ws_size,
                              hipStream_t stream) {
  const float* x     = (const float*)d_in[0];  // [2,2048,1024]
  const float* w_qkv = (const float*)d_in[1];  // [1024,3072]
  const float* w_out = (const float*)d_in[2];  // [1024,1024]
  const float* freqs = (const float*)d_in[3];  // [2048,64]
  float* out = (float*)d_out;

  char* ws = (char*)d_ws;
  unsigned short* qkvb = (unsigned short*)(ws);             // 4096*3072*2 = 25165824
  unsigned short* Qb   = (unsigned short*)(ws + 25165824);  // 8388608
  unsigned short* Kb   = (unsigned short*)(ws + 33554432);  // 8388608
  unsigned short* Vtg  = (unsigned short*)(ws + 41943040);  // 8388608
  unsigned short* attnb= (unsigned short*)(ws + 50331648);  // 8388608
  unsigned short* wqT  = (unsigned short*)(ws + 58720256);  // 6291456
  unsigned short* woT  = (unsigned short*)(ws + 65011712);  // 2097152
  // total ws use: 67108864 bytes (64 MiB)

  transpose_f32_bf16<<<dim3(96, 32), 256, 0, stream>>>(w_qkv, wqT, 1024, 3072);
  transpose_f32_bf16<<<dim3(32, 32), 256, 0, stream>>>(w_out, woT, 1024, 1024);
  gemm_bt<1, 1><<<dim3(24, 32), 256, 0, stream>>>(x, wqT, qkvb, 4096, 3072, 1024);
  prep_kernel<<<dim3(32, 16, 2), 256, 0, stream>>>(qkvb, freqs, Qb, Kb, Vtg);
  attn_mfma<<<dim3(16, 16, 2), 256, 0, stream>>>(Qb, Kb, Vtg, attnb);
  gemm_bt<0, 0><<<dim3(8, 32), 256, 0, stream>>>(attnb, woT, out, 4096, 1024, 1024);
}

// Round 4
// 151.500 us; speedup vs baseline: 5.6186x; 1.0663x over previous
//
#include <hip/hip_runtime.h>

// ---------------------------------------------------------------------------
// Fused attention block: qkv GEMM -> RoPE -> causal SDPA (MFMA) -> out GEMM
// B=2 S=2048 D=1024 H=16 DH=64. bf16 MFMA everywhere.
// MFMA fragment mapping (verified r1-r3): A/B-frag outer=lane&15, k=oct*8+e;
// C/D row=oct*4+r, col=lane&15.
// r4: dbuf K/V (1 barrier/iter), exp2-domain softmax + defer-max,
//     GEMMs via global_load_lds with XOR-swizzled source (m97 ladder).
// ---------------------------------------------------------------------------

typedef __bf16 bf16x8 __attribute__((ext_vector_type(8)));
typedef float f32x4 __attribute__((ext_vector_type(4)));

__device__ __forceinline__ unsigned short f2b(float f) {
  unsigned int u = __builtin_bit_cast(unsigned int, f);
  unsigned int lsb = (u >> 16) & 1u;
  u += 0x7fffu + lsb;  // round-to-nearest-even
  return (unsigned short)(u >> 16);
}
__device__ __forceinline__ float b2f(unsigned short h) {
  unsigned int u = ((unsigned int)h) << 16;
  return __builtin_bit_cast(float, u);
}
__device__ __forceinline__ unsigned int pk2(float a, float b) {
  return (unsigned int)f2b(a) | ((unsigned int)f2b(b) << 16);
}
__device__ __forceinline__ void unp8(uint4 v, float* f) {
  unsigned int u[4] = {v.x, v.y, v.z, v.w};
#pragma unroll
  for (int i = 0; i < 4; ++i) {
    f[2 * i] = b2f((unsigned short)(u[i] & 0xffff));
    f[2 * i + 1] = b2f((unsigned short)(u[i] >> 16));
  }
}
__device__ __forceinline__ void gload16(const void* g, void* l) {
  __builtin_amdgcn_global_load_lds(
      (const __attribute__((address_space(1))) unsigned int*)g,
      (__attribute__((address_space(3))) unsigned int*)l, 16, 0, 0);
}

// --------------------------- fp32 -> bf16 convert ---------------------------
__global__ __launch_bounds__(256) void convert_bf16(const float* __restrict__ src,
                                                    unsigned short* __restrict__ dst,
                                                    int n) {
  int i = (blockIdx.x * 256 + threadIdx.x) * 4;
  if (i + 3 < n) {
    float4 v = *(const float4*)&src[i];
    ushort4 o;
    o.x = f2b(v.x); o.y = f2b(v.y); o.z = f2b(v.z); o.w = f2b(v.w);
    *(ushort4*)&dst[i] = o;
  }
}

// -------------------- transpose [K][N] f32 -> [N][K] bf16 -------------------
__global__ __launch_bounds__(256) void transpose_f32_bf16(const float* __restrict__ src,
                                                          unsigned short* __restrict__ dst,
                                                          int K, int N) {
  __shared__ float tile[32][33];
  int n0 = blockIdx.x * 32, k0 = blockIdx.y * 32;
  int c = threadIdx.x & 31, r4 = threadIdx.x >> 5;
#pragma unroll
  for (int p = 0; p < 4; ++p) {
    int r = r4 + p * 8;
    tile[r][c] = src[(size_t)(k0 + r) * N + n0 + c];
  }
  __syncthreads();
#pragma unroll
  for (int p = 0; p < 4; ++p) {
    int r = r4 + p * 8;
    dst[(size_t)(n0 + r) * K + k0 + c] = f2b(tile[c][r]);
  }
}

// --------------------------- bf16 MFMA GEMM --------------------------------
// C[M][N] = A[M][K]*B, B given as BT[N][K], both bf16. Staging via
// global_load_lds (16B) into linear LDS with XOR-swizzled global source:
// LDS chunk p of row r holds global chunk p ^ ((r>>1)&3); fragment read at
// chunk oct ^ ((row>>1)&3) -> 2-way-minimum bank aliasing.
template <int C_BF16>
__global__ __launch_bounds__(256) void gemm_bt(const unsigned short* __restrict__ A,
                                               const unsigned short* __restrict__ BT,
                                               void* __restrict__ Cp,
                                               int M, int N, int K) {
  __shared__ unsigned short AsL[128 * 32];
  __shared__ unsigned short BsL[128 * 32];
  const int tid = threadIdx.x;
  const int m0 = blockIdx.y * 128, n0 = blockIdx.x * 128;
  const int lane = tid & 63, w = tid >> 6;
  const int wm = (w >> 1) * 64, wn = (w & 1) * 64;
  const int fr = lane & 15, oct = lane >> 4;
  const int l = lane;
  const int srow = (l >> 2);                      // 0..15 within chunk
  const int scol = ((l & 3) ^ ((l >> 3) & 3)) * 8;  // swizzled source col

  f32x4 acc[4][4] = {};

  for (int k0 = 0; k0 < K; k0 += 32) {
    __syncthreads();
#pragma unroll
    for (int p = 0; p < 2; ++p) {
      const int c = w * 2 + p;  // wave-uniform chunk id 0..7
      const int row = c * 16 + srow;
      gload16(&A[(size_t)(m0 + row) * K + k0 + scol], &AsL[c * 512 + l * 8]);
      gload16(&BT[(size_t)(n0 + row) * K + k0 + scol], &BsL[c * 512 + l * 8]);
    }
    __syncthreads();
    bf16x8 af[4], bq[4];
#pragma unroll
    for (int i = 0; i < 4; ++i) {
      int r = wm + i * 16 + fr;
      af[i] = __builtin_bit_cast(
          bf16x8, *(const uint4*)&AsL[r * 32 + (oct ^ ((r >> 1) & 3)) * 8]);
    }
#pragma unroll
    for (int j = 0; j < 4; ++j) {
      int r = wn + j * 16 + fr;
      bq[j] = __builtin_bit_cast(
          bf16x8, *(const uint4*)&BsL[r * 32 + (oct ^ ((r >> 1) & 3)) * 8]);
    }
#pragma unroll
    for (int i = 0; i < 4; ++i)
#pragma unroll
      for (int j = 0; j < 4; ++j)
        acc[i][j] = __builtin_amdgcn_mfma_f32_16x16x32_bf16(af[i], bq[j], acc[i][j], 0, 0, 0);
  }

#pragma unroll
  for (int i = 0; i < 4; ++i)
#pragma unroll
    for (int j = 0; j < 4; ++j)
#pragma unroll
      for (int r = 0; r < 4; ++r) {
        size_t idx = (size_t)(m0 + wm + i * 16 + oct * 4 + r) * N + n0 + wn + j * 16 + fr;
        if (C_BF16)
          ((unsigned short*)Cp)[idx] = f2b(acc[i][j][r]);
        else
          ((float*)Cp)[idx] = acc[i][j][r];
      }
}

// ----------------- prep: RoPE + layout (Q,K rows; V transposed) -------------
// qkvb [4096][3072] bf16. Writes Qb,Kb [b*16+h][2048][64] bf16 (Q scaled by
// 0.125*log2e for exp2-domain softmax), Vtg [b*16+h][64][2048] bf16.
__global__ __launch_bounds__(256) void prep_kernel(const unsigned short* __restrict__ qkvb,
                                                   const float* __restrict__ freqs,
                                                   unsigned short* __restrict__ Qb,
                                                   unsigned short* __restrict__ Kb,
                                                   unsigned short* __restrict__ Vtg) {
  const int sb = blockIdx.x, h = blockIdx.y, b = blockIdx.z;
  const int tid = threadIdx.x;
  __shared__ float Vs[64][65];
  const int sl = tid >> 2, c8 = (tid & 3) * 8;
  const int s = sb * 64 + sl;
  const size_t tok = (size_t)(b * 2048 + s);
  const unsigned short* row = qkvb + tok * 3072 + h * 64;
  const float QSCALE = 0.125f * 1.44269504f;

  float cl[8], snl[8], ch[8], snh[8];
#pragma unroll
  for (int e = 0; e < 8; ++e) {
    float fl = freqs[s * 64 + c8 + e];
    float fh = freqs[s * 64 + 32 + c8 + e];
    cl[e] = cosf(fl); snl[e] = sinf(fl);
    ch[e] = cosf(fh); snh[e] = sinf(fh);
  }
  const size_t obase = ((size_t)(b * 16 + h) * 2048 + s) * 64;

  // Q (scaled)
  {
    float lo[8], hi[8];
    unp8(*(const uint4*)(row + c8), lo);
    unp8(*(const uint4*)(row + 32 + c8), hi);
    float olo[8], ohi[8];
#pragma unroll
    for (int e = 0; e < 8; ++e) {
      olo[e] = (lo[e] * cl[e] - hi[e] * snl[e]) * QSCALE;
      ohi[e] = (hi[e] * ch[e] + lo[e] * snh[e]) * QSCALE;
    }
    uint4 w0, w1;
    w0.x = pk2(olo[0], olo[1]); w0.y = pk2(olo[2], olo[3]);
    w0.z = pk2(olo[4], olo[5]); w0.w = pk2(olo[6], olo[7]);
    w1.x = pk2(ohi[0], ohi[1]); w1.y = pk2(ohi[2], ohi[3]);
    w1.z = pk2(ohi[4], ohi[5]); w1.w = pk2(ohi[6], ohi[7]);
    *(uint4*)(Qb + obase + c8) = w0;
    *(uint4*)(Qb + obase + 32 + c8) = w1;
  }
  // K
  {
    float lo[8], hi[8];
    unp8(*(const uint4*)(row + 1024 + c8), lo);
    unp8(*(const uint4*)(row + 1024 + 32 + c8), hi);
    float olo[8], ohi[8];
#pragma unroll
    for (int e = 0; e < 8; ++e) {
      olo[e] = lo[e] * cl[e] - hi[e] * snl[e];
      ohi[e] = hi[e] * ch[e] + lo[e] * snh[e];
    }
    uint4 w0, w1;
    w0.x = pk2(olo[0], olo[1]); w0.y = pk2(olo[2], olo[3]);
    w0.z = pk2(olo[4], olo[5]); w0.w = pk2(olo[6], olo[7]);
    w1.x = pk2(ohi[0], ohi[1]); w1.y = pk2(ohi[2], ohi[3]);
    w1.z = pk2(ohi[4], ohi[5]); w1.w = pk2(ohi[6], ohi[7]);
    *(uint4*)(Kb + obase + c8) = w0;
    *(uint4*)(Kb + obase + 32 + c8) = w1;
  }
  // V -> LDS f32, then transposed bf16 out
  {
    float lo[8], hi[8];
    unp8(*(const uint4*)(row + 2048 + c8), lo);
    unp8(*(const uint4*)(row + 2048 + 32 + c8), hi);
#pragma unroll
    for (int e = 0; e < 8; ++e) {
      Vs[sl][c8 + e] = lo[e];
      Vs[sl][32 + c8 + e] = hi[e];
    }
  }
  __syncthreads();
  {
    const int d = tid >> 2, sc0 = (tid & 3) * 16;
    const size_t vbase = ((size_t)(b * 16 + h) * 64 + d) * 2048 + sb * 64 + sc0;
#pragma unroll
    for (int g = 0; g < 4; ++g) {
      ushort4 u;
      u.x = f2b(Vs[sc0 + g * 4 + 0][d]);
      u.y = f2b(Vs[sc0 + g * 4 + 1][d]);
      u.z = f2b(Vs[sc0 + g * 4 + 2][d]);
      u.w = f2b(Vs[sc0 + g * 4 + 3][d]);
      *(ushort4*)(Vtg + vbase + g * 4) = u;
    }
  }
}

// --------------------------- MFMA flash attention ---------------------------
// Block = (pair, h, b): q-tiles {pair, 31-pair}, 4 waves. Swapped QK^T
// (S^T = mfma(K,Q)): lane owns q-column fr. Double-buffered K/V (register
// prefetch, 1 barrier/iter). exp2-domain softmax with defer-max (THR=11).
__global__ __launch_bounds__(256) void attn_mfma(const unsigned short* __restrict__ Qb,
                                                 const unsigned short* __restrict__ Kb,
                                                 const unsigned short* __restrict__ Vtg,
                                                 unsigned short* __restrict__ attnb) {
  const int h = blockIdx.y, b = blockIdx.z;
  const int qt0 = blockIdx.x;   // 0..15
  const int qt1 = 31 - qt0;     // 16..31
  const int tid = threadIdx.x, lane = tid & 63, w = tid >> 6;
  const int fr = lane & 15, oct = lane >> 4;

  __shared__ unsigned short Ks[2][64][72];
  __shared__ unsigned short Vt[2][64][72];
  __shared__ unsigned short Pl[4][2][16][72];

  const size_t bh = (size_t)(b * 16 + h);
  const int qtv[2] = {qt0, qt1};

  bf16x8 qf[2][2];
#pragma unroll
  for (int tl = 0; tl < 2; ++tl) {
    const unsigned short* Qp = Qb + (bh * 2048 + qtv[tl] * 64 + w * 16 + fr) * 64;
    qf[tl][0] = __builtin_bit_cast(bf16x8, *(const uint4*)(Qp + oct * 8));
    qf[tl][1] = __builtin_bit_cast(bf16x8, *(const uint4*)(Qp + 32 + oct * 8));
  }

  float m_prev[2] = {-1e30f, -1e30f};
  float l_prev[2] = {0.f, 0.f};
  f32x4 acc[2][4] = {};  // acc[tl][t2][r] = O[q=w*16+oct*4+r][d=t2*16+fr]

  const int sk = tid >> 2, sc = (tid & 3) * 16;
  const unsigned short* Kp = Kb + bh * 2048 * 64;
  const unsigned short* Vp = Vtg + bh * 64 * 2048;

  uint4 kr0, kr1, vr0, vr1;
  auto load_tile = [&](int kb) {
    const unsigned short* ks = Kp + (size_t)(kb * 64 + sk) * 64 + sc;
    kr0 = *(const uint4*)ks;
    kr1 = *(const uint4*)(ks + 8);
    const unsigned short* vs = Vp + (size_t)sk * 2048 + kb * 64 + sc;
    vr0 = *(const uint4*)vs;
    vr1 = *(const uint4*)(vs + 8);
  };
  auto store_tile = [&](int buf) {
    *(uint4*)&Ks[buf][sk][sc] = kr0;
    *(uint4*)&Ks[buf][sk][sc + 8] = kr1;
    *(uint4*)&Vt[buf][sk][sc] = vr0;
    *(uint4*)&Vt[buf][sk][sc + 8] = vr1;
  };

  load_tile(0);
  store_tile(0);
  __syncthreads();
  int cur = 0;

  for (int kb = 0; kb <= qt1; ++kb) {
    if (kb < qt1) load_tile(kb + 1);  // prefetch next tile into registers

    const bool doA = (kb <= qt0);

    // K fragments (shared by both q-tiles)
    bf16x8 kf0[4], kf1[4];
#pragma unroll
    for (int t = 0; t < 4; ++t) {
      kf0[t] = __builtin_bit_cast(bf16x8, *(const uint4*)&Ks[cur][t * 16 + fr][oct * 8]);
      kf1[t] = __builtin_bit_cast(bf16x8, *(const uint4*)&Ks[cur][t * 16 + fr][32 + oct * 8]);
    }

    // S^T (log2-domain): s4[tl][t][r] = S[q=qt*64+w*16+fr][k=kb*64+t*16+oct*4+r]
    f32x4 s4[2][4];
#pragma unroll
    for (int tl = 0; tl < 2; ++tl) {
      if (tl == 0 && !doA) continue;
#pragma unroll
      for (int t = 0; t < 4; ++t) {
        f32x4 s = {};
        s = __builtin_amdgcn_mfma_f32_16x16x32_bf16(kf0[t], qf[tl][0], s, 0, 0, 0);
        s = __builtin_amdgcn_mfma_f32_16x16x32_bf16(kf1[t], qf[tl][1], s, 0, 0, 0);
        s4[tl][t] = s;
      }
      if (kb == qtv[tl]) {  // diagonal tile: causal mask (k > q)
#pragma unroll
        for (int t = 0; t < 4; ++t)
#pragma unroll
          for (int r = 0; r < 4; ++r)
            if (t * 16 + oct * 4 + r > w * 16 + fr) s4[tl][t][r] = -1e30f;
      }
    }

    // online softmax per lane (q-column = fr); defer-max rescale
    float cfv[2];
    bool need[2] = {false, false};
#pragma unroll
    for (int tl = 0; tl < 2; ++tl) {
      if (tl == 0 && !doA) continue;
      float pm = -1e30f;
#pragma unroll
      for (int t = 0; t < 4; ++t)
#pragma unroll
        for (int r = 0; r < 4; ++r) pm = fmaxf(pm, s4[tl][t][r]);
      pm = fmaxf(pm, __shfl_xor(pm, 16));
      pm = fmaxf(pm, __shfl_xor(pm, 32));
      need[tl] = __any(pm - m_prev[tl] > 11.0f);
      float mnew = m_prev[tl], cf = 1.0f;
      if (need[tl]) {
        mnew = fmaxf(m_prev[tl], pm);
        cf = exp2f(m_prev[tl] - mnew);
        m_prev[tl] = mnew;
      }
      cfv[tl] = cf;
      float psum = 0.f;
#pragma unroll
      for (int t = 0; t < 4; ++t) {
#pragma unroll
        for (int r = 0; r < 4; ++r) {
          float p = exp2f(s4[tl][t][r] - mnew);
          s4[tl][t][r] = p;
          psum += p;
        }
        uint2 pw;
        pw.x = pk2(s4[tl][t][0], s4[tl][t][1]);
        pw.y = pk2(s4[tl][t][2], s4[tl][t][3]);
        *(uint2*)&Pl[w][tl][fr][t * 16 + oct * 4] = pw;  // P[q][k] layout
      }
      psum += __shfl_xor(psum, 16);
      psum += __shfl_xor(psum, 32);
      l_prev[tl] = l_prev[tl] * cfv[tl] + psum;
    }

    // V fragments (shared) + PV
    bf16x8 vf0[4], vf1[4];
#pragma unroll
    for (int t2 = 0; t2 < 4; ++t2) {
      vf0[t2] = __builtin_bit_cast(bf16x8, *(const uint4*)&Vt[cur][t2 * 16 + fr][oct * 8]);
      vf1[t2] = __builtin_bit_cast(bf16x8, *(const uint4*)&Vt[cur][t2 * 16 + fr][32 + oct * 8]);
    }
#pragma unroll
    for (int tl = 0; tl < 2; ++tl) {
      if (tl == 0 && !doA) continue;
      if (need[tl]) {  // wave-uniform branch
        float cfr[4];
#pragma unroll
        for (int r = 0; r < 4; ++r) cfr[r] = __shfl(cfv[tl], oct * 4 + r);
#pragma unroll
        for (int t2 = 0; t2 < 4; ++t2)
#pragma unroll
          for (int r = 0; r < 4; ++r) acc[tl][t2][r] *= cfr[r];
      }
      const bf16x8 pf0 =
          __builtin_bit_cast(bf16x8, *(const uint4*)&Pl[w][tl][fr][oct * 8]);
      const bf16x8 pf1 =
          __builtin_bit_cast(bf16x8, *(const uint4*)&Pl[w][tl][fr][32 + oct * 8]);
#pragma unroll
      for (int t2 = 0; t2 < 4; ++t2) {
        f32x4 a = acc[tl][t2];
        a = __builtin_amdgcn_mfma_f32_16x16x32_bf16(pf0, vf0[t2], a, 0, 0, 0);
        a = __builtin_amdgcn_mfma_f32_16x16x32_bf16(pf1, vf1[t2], a, 0, 0, 0);
        acc[tl][t2] = a;
      }
    }

    if (kb < qt1) store_tile(cur ^ 1);  // waits vmcnt, writes other buffer
    __syncthreads();
    cur ^= 1;
  }

  // epilogue: normalize by l (transposed via shfl), write bf16
#pragma unroll
  for (int tl = 0; tl < 2; ++tl) {
    float linv[4];
#pragma unroll
    for (int r = 0; r < 4; ++r) linv[r] = 1.f / __shfl(l_prev[tl], oct * 4 + r);
#pragma unroll
    for (int r = 0; r < 4; ++r) {
      size_t orow = (size_t)(b * 2048 + qtv[tl] * 64 + w * 16 + oct * 4 + r);
#pragma unroll
      for (int t2 = 0; t2 < 4; ++t2)
        attnb[orow * 1024 + h * 64 + t2 * 16 + fr] = f2b(acc[tl][t2][r] * linv[r]);
    }
  }
}

// ---------------------------------------------------------------------------
extern "C" void kernel_launch(void* const* d_in, const int* in_sizes, int n_in,
                              void* d_out, int out_size, void* d_ws, size_t ws_size,
                              hipStream_t stream) {
  const float* x     = (const float*)d_in[0];  // [2,2048,1024]
  const float* w_qkv = (const float*)d_in[1];  // [1024,3072]
  const float* w_out = (const float*)d_in[2];  // [1024,1024]
  const float* freqs = (const float*)d_in[3];  // [2048,64]
  float* out = (float*)d_out;

  char* ws = (char*)d_ws;
  unsigned short* qkvb = (unsigned short*)(ws);             // 25165824
  unsigned short* Qb   = (unsigned short*)(ws + 25165824);  // 8388608
  unsigned short* Kb   = (unsigned short*)(ws + 33554432);  // 8388608
  unsigned short* Vtg  = (unsigned short*)(ws + 41943040);  // 8388608
  unsigned short* attnb= (unsigned short*)(ws + 50331648);  // 8388608
  unsigned short* wqT  = (unsigned short*)(ws + 58720256);  // 6291456
  unsigned short* woT  = (unsigned short*)(ws + 65011712);  // 2097152
  unsigned short* xb   = (unsigned short*)(ws + 67108864);  // 8388608
  // total ws use: 75497472 bytes (72 MiB)

  convert_bf16<<<4096, 256, 0, stream>>>(x, xb, 4096 * 1024);
  transpose_f32_bf16<<<dim3(96, 32), 256, 0, stream>>>(w_qkv, wqT, 1024, 3072);
  transpose_f32_bf16<<<dim3(32, 32), 256, 0, stream>>>(w_out, woT, 1024, 1024);
  gemm_bt<1><<<dim3(24, 32), 256, 0, stream>>>(xb, wqT, qkvb, 4096, 3072, 1024);
  prep_kernel<<<dim3(32, 16, 2), 256, 0, stream>>>(qkvb, freqs, Qb, Kb, Vtg);
  attn_mfma<<<dim3(16, 16, 2), 256, 0, stream>>>(Qb, Kb, Vtg, attnb);
  gemm_bt<0><<<dim3(8, 32), 256, 0, stream>>>(attnb, woT, out, 4096, 1024, 1024);
}